// Round 1
// baseline (606.219 us; speedup 1.0000x reference)
//
#include <hip/hip_runtime.h>
#include <math.h>

#define B 2
#define S 256
#define H 768
#define L 50
#define E 512
#define W 10
#define NSPAN 2515
#define KTOP 102
#define D3 2304
#define N6 6912

// workspace float offsets
#define OFF_T    ((size_t)0)         // 1024*768
#define OFF_EMB  ((size_t)786432)    // 512*768
#define OFF_G    ((size_t)1179648)   // 512*6912
#define OFF_TOKD ((size_t)4718592)   // 512*8
#define OFF_MENT ((size_t)4722688)   // 5120
#define OFF_SJ   ((size_t)4727808)   // 5120
#define OFF_SI   ((size_t)4732928)   // 5120
#define OFF_SELJ ((size_t)4738048)   // 256
#define OFF_SELI ((size_t)4738304)   // 256
#define OFF_INT  ((size_t)4738560)   // int region

// ---------------------------------------------------------------- edge grouping
__global__ __launch_bounds__(1024) void k_group(
    const int* __restrict__ esrc, const int* __restrict__ etgt,
    const int* __restrict__ elab, int* __restrict__ cnt,
    int* __restrict__ off, int* __restrict__ edges) {
    __shared__ int lcnt[L];
    __shared__ int loff[L];
    int t = threadIdx.x;  // t == global edge id, blockDim == B*E == 1024
    if (t < L) lcnt[t] = 0;
    __syncthreads();
    int lab = elab[t], src = esrc[t], tgt = etgt[t];
    bool valid = (lab >= 0) && (lab < L) && (src >= 0) && (src < S) && (tgt >= 0) && (tgt < S);
    int mypos = -1;
    if (valid) mypos = atomicAdd(&lcnt[lab], 1);
    __syncthreads();
    if (t == 0) {
        int acc = 0;
        for (int l = 0; l < L; l++) { loff[l] = acc; acc += lcnt[l]; }
    }
    __syncthreads();
    if (valid) edges[loff[lab] + mypos] = t;
    if (t < L) { cnt[t] = lcnt[t]; off[t] = loff[t]; }
}

// ---------------------------------------------------------------- per-edge GCN transform
// grid (H/16, L), block 256. Stages 16 W-rows in LDS (read once from HBM),
// each wave owns one edge at a time (x vector in regs), shuffle-reduced dots.
__global__ __launch_bounds__(256) void k_gcn(
    const float* __restrict__ hidden, const float* __restrict__ gcnW,
    const float* __restrict__ gcnb, const int* __restrict__ cnt,
    const int* __restrict__ off, const int* __restrict__ edges,
    const int* __restrict__ esrc, float* __restrict__ T) {
    int l = blockIdx.y;
    int n = cnt[l];
    if (n == 0) return;
    int row0 = blockIdx.x * 16;
    __shared__ float wlds[16 * H];  // 48 KB
    const float4* wg = (const float4*)(gcnW + ((size_t)l * H + row0) * H);
    float4* wl4 = (float4*)wlds;
#pragma unroll
    for (int i = 0; i < 12; i++) wl4[threadIdx.x + 256 * i] = wg[threadIdx.x + 256 * i];
    __syncthreads();
    int wave = threadIdx.x >> 6, lane = threadIdx.x & 63;
    int o = off[l];
    for (int i = wave; i < n; i += 4) {
        int g = edges[o + i];
        int b = g / E;
        int s = esrc[g];
        const float* x = hidden + ((size_t)(b * S + s)) * H;
        float xr[12];
#pragma unroll
        for (int m = 0; m < 12; m++) xr[m] = x[lane + 64 * m];
        float* tout = T + (size_t)g * H + row0;
        const float* bp = gcnb + l * H + row0;
#pragma unroll
        for (int r = 0; r < 16; r++) {
            float acc = 0.f;
            const float* wr = wlds + r * H;
#pragma unroll
            for (int m = 0; m < 12; m++) acc = fmaf(wr[lane + 64 * m], xr[m], acc);
#pragma unroll
            for (int d = 32; d; d >>= 1) acc += __shfl_down(acc, d);
            if (lane == 0) tout[r] = acc + bp[r];
        }
    }
}

// ---------------------------------------------------------------- deterministic scatter + relu + residual
__global__ __launch_bounds__(256) void k_combine(
    const float* __restrict__ hidden, const int* __restrict__ esrc,
    const int* __restrict__ etgt, const int* __restrict__ elab,
    const float* __restrict__ T, float* __restrict__ emb) {
    __shared__ int tv[E];
    int bs = blockIdx.x;
    int b = bs / S, s = bs % S;
    for (int e = threadIdx.x; e < E; e += 256) {
        int g = b * E + e;
        int lab = elab[g], sr = esrc[g], tg = etgt[g];
        bool valid = (lab >= 0) && (lab < L) && (sr >= 0) && (sr < S) && (tg >= 0) && (tg < S);
        tv[e] = valid ? tg : -1;
    }
    __syncthreads();
    float acc0 = 0.f, acc1 = 0.f, acc2 = 0.f;
    for (int e = 0; e < E; e++) {
        if (tv[e] == s) {  // block-uniform branch
            const float* t = T + ((size_t)(b * E + e)) * H;
            acc0 += t[threadIdx.x];
            acc1 += t[threadIdx.x + 256];
            acc2 += t[threadIdx.x + 512];
        }
    }
    const float* hp = hidden + (size_t)bs * H;
    float* op = emb + (size_t)bs * H;
    op[threadIdx.x]       = hp[threadIdx.x]       + fmaxf(acc0, 0.f);
    op[threadIdx.x + 256] = hp[threadIdx.x + 256] + fmaxf(acc1, 0.f);
    op[threadIdx.x + 512] = hp[threadIdx.x + 512] + fmaxf(acc2, 0.f);
}

// ---------------------------------------------------------------- per-token dots: attn score + 6 ant_w dots
__global__ __launch_bounds__(256) void k_tokdots(
    const float* __restrict__ emb, const float* __restrict__ attnw,
    const float* __restrict__ antw, float* __restrict__ tokd) {
    int wave = threadIdx.x >> 6, lane = threadIdx.x & 63;
    int tok = blockIdx.x * 4 + wave;
    const float* x = emb + (size_t)tok * H;
    float p[7] = {0, 0, 0, 0, 0, 0, 0};
#pragma unroll
    for (int m = 0; m < 12; m++) {
        int k = lane + 64 * m;
        float xv = x[k];
        p[0] = fmaf(attnw[k], xv, p[0]);
#pragma unroll
        for (int q = 0; q < 6; q++) p[1 + q] = fmaf(antw[q * H + k], xv, p[1 + q]);
    }
#pragma unroll
    for (int q = 0; q < 7; q++) {
        float v = p[q];
#pragma unroll
        for (int d = 32; d; d >>= 1) v += __shfl_down(v, d);
        p[q] = v;
    }
    if (lane == 0) {
        float* o = tokd + (size_t)tok * 8;
#pragma unroll
        for (int q = 0; q < 7; q++) o[q] = p[q];
    }
}

// ---------------------------------------------------------------- G = emb @ W1-blocks^T  (M=512, N=6912, K=768)
// Per col n = blk*2304 + e : G[m][n] = sum_d emb[m][d] * W1[e][blk*768+d]
__global__ __launch_bounds__(256) void k_gemm(
    const float* __restrict__ A, const float* __restrict__ W1, float* __restrict__ G) {
    __shared__ float As[32][68];
    __shared__ float Bs[32][132];
    int n0 = blockIdx.x * 128;
    int m0 = blockIdx.y * 64;
    int blk = n0 / D3;          // 2304 % 128 == 0 -> tiles never straddle blocks
    int e0 = n0 - blk * D3;
    const float* Ap = A + (size_t)m0 * H;
    const float* Bp = W1 + (size_t)e0 * D3 + blk * H;
    int tx = threadIdx.x & 15, ty = threadIdx.x >> 4;
    float acc[4][8];
#pragma unroll
    for (int r = 0; r < 4; r++)
#pragma unroll
        for (int c = 0; c < 8; c++) acc[r][c] = 0.f;
    for (int kt = 0; kt < H; kt += 32) {
#pragma unroll
        for (int i = 0; i < 2; i++) {
            int ff = threadIdx.x + 256 * i;
            int row = ff >> 3, c4 = (ff & 7) * 4;
            float4 v = *(const float4*)(Ap + (size_t)row * H + kt + c4);
            As[c4 + 0][row] = v.x; As[c4 + 1][row] = v.y;
            As[c4 + 2][row] = v.z; As[c4 + 3][row] = v.w;
        }
#pragma unroll
        for (int i = 0; i < 4; i++) {
            int ff = threadIdx.x + 256 * i;
            int row = ff >> 3, c4 = (ff & 7) * 4;
            float4 v = *(const float4*)(Bp + (size_t)row * D3 + kt + c4);
            Bs[c4 + 0][row] = v.x; Bs[c4 + 1][row] = v.y;
            Bs[c4 + 2][row] = v.z; Bs[c4 + 3][row] = v.w;
        }
        __syncthreads();
#pragma unroll
        for (int k = 0; k < 32; k++) {
            float4 a  = *(const float4*)&As[k][ty * 4];
            float4 b0 = *(const float4*)&Bs[k][tx * 8];
            float4 b1 = *(const float4*)&Bs[k][tx * 8 + 4];
            float av[4] = {a.x, a.y, a.z, a.w};
            float bv[8] = {b0.x, b0.y, b0.z, b0.w, b1.x, b1.y, b1.z, b1.w};
#pragma unroll
            for (int r = 0; r < 4; r++)
#pragma unroll
                for (int c = 0; c < 8; c++) acc[r][c] = fmaf(av[r], bv[c], acc[r][c]);
        }
        __syncthreads();
    }
#pragma unroll
    for (int r = 0; r < 4; r++) {
        float* gp = G + (size_t)(m0 + ty * 4 + r) * N6 + n0 + tx * 8;
        *(float4*)gp       = make_float4(acc[r][0], acc[r][1], acc[r][2], acc[r][3]);
        *(float4*)(gp + 4) = make_float4(acc[r][4], acc[r][5], acc[r][6], acc[r][7]);
    }
}

// ---------------------------------------------------------------- per-start span group: softmax, mention, sj/si
// one block per (b, start); handles the <=10 spans sharing that start.
__global__ __launch_bounds__(256) void k_span(
    const float* __restrict__ G, const float* __restrict__ tokd,
    const float* __restrict__ b1, const float* __restrict__ w2,
    const float* __restrict__ b2, float* __restrict__ ment,
    float* __restrict__ sjA, float* __restrict__ siA) {
    int b = blockIdx.x / S, start = blockIdx.x % S;
    int nw = min(W, S - start);
    int tail = S - start;
    int base = (start <= S - W) ? start * W
             : (S - W + 1) * W + ((W - 1) * W / 2 - tail * (tail + 1) / 2);
    __shared__ float sc[W];
    __shared__ float aw[W][W];
    __shared__ float red[4];
    int tid = threadIdx.x;
    if (tid < nw) sc[tid] = tokd[(size_t)(b * S + start + tid) * 8];
    __syncthreads();
    if (tid < nw) {
        int w = tid;  // span of width w+1
        float mx = sc[0];
        for (int j = 1; j <= w; j++) mx = fmaxf(mx, sc[j]);
        float sum = 0.f;
        for (int j = 0; j <= w; j++) { float e = expf(sc[j] - mx); aw[w][j] = e; sum += e; }
        float inv = 1.f / sum;
        for (int j = 0; j <= w; j++) aw[w][j] *= inv;
        const float* td = tokd + (size_t)(b * S) * 8;
        float sj = td[start * 8 + 1] + td[(start + w) * 8 + 2];
        float si = td[start * 8 + 4] + td[(start + w) * 8 + 5];
        for (int j = 0; j <= w; j++) {
            sj = fmaf(aw[w][j], td[(start + j) * 8 + 3], sj);
            si = fmaf(aw[w][j], td[(start + j) * 8 + 6], si);
        }
        sjA[b * NSPAN + base + w] = sj;
        siA[b * NSPAN + base + w] = si;
    }
    __syncthreads();
    float mloc[W];
#pragma unroll
    for (int w = 0; w < W; w++) mloc[w] = 0.f;
    const float* Gb = G + (size_t)(b * S) * N6;
    for (int e = tid; e < D3; e += 256) {
        float a = Gb[(size_t)start * N6 + e] + b1[e];
        float w2e = w2[e];
        float cj[W], bm[W];
#pragma unroll
        for (int j = 0; j < W; j++) {
            if (j < nw) {
                cj[j] = Gb[(size_t)(start + j) * N6 + 2 * D3 + e];
                bm[j] = Gb[(size_t)(start + j) * N6 + D3 + e];
            } else { cj[j] = 0.f; bm[j] = 0.f; }
        }
#pragma unroll
        for (int w = 0; w < W; w++) {
            if (w < nw) {
                float pre = a + bm[w];
#pragma unroll
                for (int j = 0; j <= w; j++) pre = fmaf(aw[w][j], cj[j], pre);
                mloc[w] += fmaxf(pre, 0.f) * w2e;
            }
        }
    }
    int wave = tid >> 6, lane = tid & 63;
#pragma unroll
    for (int w = 0; w < W; w++) {
        float v = mloc[w];
#pragma unroll
        for (int d = 32; d; d >>= 1) v += __shfl_down(v, d);
        if (lane == 0) red[wave] = v;
        __syncthreads();
        if (tid == 0 && w < nw)
            ment[b * NSPAN + base + w] = red[0] + red[1] + red[2] + red[3] + b2[0];
        __syncthreads();
    }
}

// ---------------------------------------------------------------- top-k selection (stable, desc, ties -> lower idx)
__global__ __launch_bounds__(256) void k_topk(
    const float* __restrict__ ment, const float* __restrict__ sjA,
    const float* __restrict__ siA, float* __restrict__ selj, float* __restrict__ seli) {
    __shared__ float vals[NSPAN];
    __shared__ float rv[4];
    __shared__ int ri[4];
    __shared__ int winner;
    int b = blockIdx.x, tid = threadIdx.x;
    int wave = tid >> 6, lane = tid & 63;
    for (int n = tid; n < NSPAN; n += 256) vals[n] = ment[b * NSPAN + n];
    __syncthreads();
    for (int it = 0; it < KTOP; it++) {
        float bv = -3.0e38f; int bi = 1 << 30;
        for (int n = tid; n < NSPAN; n += 256) {
            float v = vals[n];
            if (v > bv) { bv = v; bi = n; }  // strict > keeps lowest index within thread
        }
#pragma unroll
        for (int d = 32; d; d >>= 1) {
            float ov = __shfl_down(bv, d);
            int   oi = __shfl_down(bi, d);
            if (ov > bv || (ov == bv && oi < bi)) { bv = ov; bi = oi; }
        }
        if (lane == 0) { rv[wave] = bv; ri[wave] = bi; }
        __syncthreads();
        if (tid == 0) {
            float wv = rv[0]; int wi = ri[0];
            for (int q = 1; q < 4; q++) {
                if (rv[q] > wv || (rv[q] == wv && ri[q] < wi)) { wv = rv[q]; wi = ri[q]; }
            }
            winner = wi;
            selj[b * KTOP + it] = sjA[b * NSPAN + wi];
            seli[b * KTOP + it] = siA[b * NSPAN + wi];
            vals[wi] = -3.0e38f;
        }
        __syncthreads();
        (void)winner;
    }
}

// ---------------------------------------------------------------- antecedent matrix + log-softmax
__global__ __launch_bounds__(128) void k_ant(
    const float* __restrict__ selj, const float* __restrict__ seli,
    const float* __restrict__ antb, float* __restrict__ out) {
    int b = blockIdx.x / KTOP, i = blockIdx.x % KTOP;
    int c = threadIdx.x;
    float v = -3.0e38f;
    if (c == 0) v = 0.f;
    else if (c <= KTOP) {
        int j = c - 1;
        v = (j >= i) ? -1e10f : (selj[b * KTOP + j] + seli[b * KTOP + i] + antb[0]);
    }
    __shared__ float r2[2];
    int wave = c >> 6, lane = c & 63;
    float mv = v;
#pragma unroll
    for (int d = 32; d; d >>= 1) mv = fmaxf(mv, __shfl_down(mv, d));
    if (lane == 0) r2[wave] = mv;
    __syncthreads();
    float mx = fmaxf(r2[0], r2[1]);
    __syncthreads();
    float ex = (c <= KTOP) ? expf(v - mx) : 0.f;
    float sv = ex;
#pragma unroll
    for (int d = 32; d; d >>= 1) sv += __shfl_down(sv, d);
    if (lane == 0) r2[wave] = sv;
    __syncthreads();
    float sm = r2[0] + r2[1];
    if (c <= KTOP)
        out[(size_t)(b * KTOP + i) * (KTOP + 1) + c] = logf(ex / sm + 1e-10f);
}

extern "C" void kernel_launch(void* const* d_in, const int* in_sizes, int n_in,
                              void* d_out, int out_size, void* d_ws, size_t ws_size,
                              hipStream_t stream) {
    (void)in_sizes; (void)n_in; (void)out_size; (void)ws_size;
    const float* hidden = (const float*)d_in[0];
    const int*   esrc   = (const int*)d_in[2];
    const int*   etgt   = (const int*)d_in[3];
    const int*   elab   = (const int*)d_in[4];
    const float* gcnW   = (const float*)d_in[5];
    const float* gcnb   = (const float*)d_in[6];
    const float* attnw  = (const float*)d_in[7];
    const float* msW1   = (const float*)d_in[9];
    const float* msb1   = (const float*)d_in[10];
    const float* msw2   = (const float*)d_in[11];
    const float* msb2   = (const float*)d_in[12];
    const float* antw   = (const float*)d_in[13];
    const float* antb   = (const float*)d_in[14];
    float* out = (float*)d_out;

    float* wsf  = (float*)d_ws;
    float* T    = wsf + OFF_T;
    float* emb  = wsf + OFF_EMB;
    float* G    = wsf + OFF_G;
    float* tokd = wsf + OFF_TOKD;
    float* ment = wsf + OFF_MENT;
    float* sjA  = wsf + OFF_SJ;
    float* siA  = wsf + OFF_SI;
    float* selj = wsf + OFF_SELJ;
    float* seli = wsf + OFF_SELI;
    int* wsi   = (int*)(wsf + OFF_INT);
    int* cnt   = wsi;
    int* off   = wsi + 64;
    int* edges = wsi + 128;

    k_group<<<1, B * E, 0, stream>>>(esrc, etgt, elab, cnt, off, edges);
    k_gcn<<<dim3(H / 16, L), 256, 0, stream>>>(hidden, gcnW, gcnb, cnt, off, edges, esrc, T);
    k_combine<<<B * S, 256, 0, stream>>>(hidden, esrc, etgt, elab, T, emb);
    k_tokdots<<<B * S / 4, 256, 0, stream>>>(emb, attnw, antw, tokd);
    k_gemm<<<dim3(N6 / 128, B * S / 64), 256, 0, stream>>>(emb, msW1, G);
    k_span<<<B * S, 256, 0, stream>>>(G, tokd, msb1, msw2, msb2, ment, sjA, siA);
    k_topk<<<B, 256, 0, stream>>>(ment, sjA, siA, selj, seli);
    k_ant<<<B * KTOP, 128, 0, stream>>>(selj, seli, antb, out);
}

// Round 2
// 368.147 us; speedup vs baseline: 1.6467x; 1.6467x over previous
//
#include <hip/hip_runtime.h>
#include <math.h>

#define B 2
#define S 256
#define H 768
#define L 50
#define E 512
#define W 10
#define NSPAN 2515
#define KTOP 102
#define D3 2304
#define N6 6912

// workspace float offsets
#define OFF_GOUT ((size_t)0)         // 512*768
#define OFF_EMB  ((size_t)393216)    // 512*768
#define OFF_G    ((size_t)786432)    // 512*6912
#define OFF_TOKD ((size_t)4325376)   // 512*8
#define OFF_MENT ((size_t)4329472)   // 5120
#define OFF_SJ   ((size_t)4334592)   // 5120
#define OFF_SI   ((size_t)4339712)   // 5120
#define OFF_SELJ ((size_t)4344832)   // 256
#define OFF_SELI ((size_t)4345088)   // 256
#define OFF_INT  ((size_t)4345344)   // int region

// ---------------------------------------------------------------- edge grouping
__global__ __launch_bounds__(1024) void k_group(
    const int* __restrict__ esrc, const int* __restrict__ etgt,
    const int* __restrict__ elab, int* __restrict__ cnt,
    int* __restrict__ off, int* __restrict__ edges) {
    __shared__ int lcnt[L];
    __shared__ int loff[L];
    int t = threadIdx.x;  // t == global edge id, blockDim == B*E == 1024
    if (t < L) lcnt[t] = 0;
    __syncthreads();
    int lab = elab[t], src = esrc[t], tgt = etgt[t];
    bool valid = (lab >= 0) && (lab < L) && (src >= 0) && (src < S) && (tgt >= 0) && (tgt < S);
    int mypos = -1;
    if (valid) mypos = atomicAdd(&lcnt[lab], 1);
    __syncthreads();
    if (t == 0) {
        int acc = 0;
        for (int l = 0; l < L; l++) { loff[l] = acc; acc += lcnt[l]; }
    }
    __syncthreads();
    if (valid) edges[loff[lab] + mypos] = t;
    if (t < L) { cnt[t] = lcnt[t]; off[t] = loff[t]; }
}

// ---------------------------------------------------------------- GCN as per-label GEMM tiles
// grid (12 row-tiles, L, 2 k-splits), block 256. Output tile 64 rows x 32 edges,
// thread tile 4x2, accumulates in registers, atomicAdd epilogue into gout.
#define GK 384
__global__ __launch_bounds__(256) void k_gcn(
    const float* __restrict__ hidden, const float* __restrict__ gcnW,
    const float* __restrict__ gcnb, const int* __restrict__ cnt,
    const int* __restrict__ off, const int* __restrict__ edges,
    const int* __restrict__ esrc, const int* __restrict__ etgt,
    float* __restrict__ gout) {
    int l = blockIdx.y;
    int n = cnt[l];
    if (n == 0) return;
    int row0 = blockIdx.x * 64;
    int kbase = blockIdx.z * GK;
    __shared__ float Ws[32][68];   // [k][row], padded
    __shared__ float Xs[32][34];   // [k][edge], padded even for b64 align
    __shared__ int srow[32];
    __shared__ int trow[32];
    int tid = threadIdx.x;
    int tx = tid & 15, ty = tid >> 4;
    int o = off[l];
    for (int e0 = 0; e0 < n; e0 += 32) {
        int nv = min(32, n - e0);
        if (tid < 32) {
            int sr = 0, tr = 0;
            if (tid < nv) {
                int g = edges[o + e0 + tid];
                int bb = g / E;
                sr = (bb * S + esrc[g]) * H;
                tr = (bb * S + etgt[g]) * H;
            }
            srow[tid] = sr;
            trow[tid] = tr;
        }
        __syncthreads();
        float acc[4][2];
#pragma unroll
        for (int r = 0; r < 4; r++) { acc[r][0] = 0.f; acc[r][1] = 0.f; }
        for (int kc = 0; kc < GK; kc += 32) {
            int k0 = kbase + kc;
            // stage W: 64 rows x 32 k, transposed into Ws[k][r]
#pragma unroll
            for (int j = 0; j < 2; j++) {
                int f = tid + 256 * j;
                int r = f >> 3, kq = (f & 7) * 4;
                float4 v = *(const float4*)(gcnW + ((size_t)l * H + row0 + r) * H + k0 + kq);
                Ws[kq + 0][r] = v.x; Ws[kq + 1][r] = v.y;
                Ws[kq + 2][r] = v.z; Ws[kq + 3][r] = v.w;
            }
            // stage X: 32 edges x 32 k into Xs[k][e]
#pragma unroll
            for (int j = 0; j < 4; j++) {
                int f = tid + 256 * j;
                int e = f >> 5, kk = f & 31;
                Xs[kk][e] = hidden[srow[e] + k0 + kk];
            }
            __syncthreads();
#pragma unroll
            for (int k = 0; k < 32; k++) {
                float4 a = *(const float4*)&Ws[k][ty * 4];
                float2 x2 = *(const float2*)&Xs[k][tx * 2];
                acc[0][0] = fmaf(a.x, x2.x, acc[0][0]);
                acc[1][0] = fmaf(a.y, x2.x, acc[1][0]);
                acc[2][0] = fmaf(a.z, x2.x, acc[2][0]);
                acc[3][0] = fmaf(a.w, x2.x, acc[3][0]);
                acc[0][1] = fmaf(a.x, x2.y, acc[0][1]);
                acc[1][1] = fmaf(a.y, x2.y, acc[1][1]);
                acc[2][1] = fmaf(a.z, x2.y, acc[2][1]);
                acc[3][1] = fmaf(a.w, x2.y, acc[3][1]);
            }
            __syncthreads();
        }
        const float* bp = gcnb + l * H + row0 + ty * 4;
        bool addb = (blockIdx.z == 0);
#pragma unroll
        for (int e = 0; e < 2; e++) {
            int ei = tx * 2 + e;
            if (ei < nv) {
                int base = trow[ei] + row0 + ty * 4;
#pragma unroll
                for (int r = 0; r < 4; r++) {
                    float v = acc[r][e];
                    if (addb) v += bp[r];
                    atomicAdd(&gout[base + r], v);
                }
            }
        }
        __syncthreads();
    }
}

// ---------------------------------------------------------------- emb = hidden + relu(gout), plus per-token dots
__global__ __launch_bounds__(256) void k_embdots(
    const float* __restrict__ hidden, const float* __restrict__ gout,
    const float* __restrict__ attnw, const float* __restrict__ antw,
    float* __restrict__ emb, float* __restrict__ tokd) {
    int wave = threadIdx.x >> 6, lane = threadIdx.x & 63;
    int tok = blockIdx.x * 4 + wave;
    const float* hp = hidden + (size_t)tok * H;
    const float* gp = gout + (size_t)tok * H;
    float* ep = emb + (size_t)tok * H;
    float p[7] = {0, 0, 0, 0, 0, 0, 0};
#pragma unroll
    for (int m = 0; m < 12; m++) {
        int k = lane + 64 * m;
        float e = hp[k] + fmaxf(gp[k], 0.f);
        ep[k] = e;
        p[0] = fmaf(attnw[k], e, p[0]);
#pragma unroll
        for (int q = 0; q < 6; q++) p[1 + q] = fmaf(antw[q * H + k], e, p[1 + q]);
    }
#pragma unroll
    for (int q = 0; q < 7; q++) {
        float v = p[q];
#pragma unroll
        for (int d = 32; d; d >>= 1) v += __shfl_down(v, d);
        p[q] = v;
    }
    if (lane == 0) {
        float* o = tokd + (size_t)tok * 8;
#pragma unroll
        for (int q = 0; q < 7; q++) o[q] = p[q];
    }
}

// ---------------------------------------------------------------- G = emb @ W1-blocks^T  (M=512, N=6912, K=768)
// 64x128 tile, reg-prefetch pipelined.
__global__ __launch_bounds__(256) void k_gemm(
    const float* __restrict__ A, const float* __restrict__ W1, float* __restrict__ G) {
    __shared__ float As[32][68];
    __shared__ float Bs[32][132];
    int n0 = blockIdx.x * 128;
    int m0 = blockIdx.y * 64;
    int blk = n0 / D3;          // 2304 % 128 == 0 -> tiles never straddle blocks
    int e0 = n0 - blk * D3;
    const float* Ap = A + (size_t)m0 * H;
    const float* Bp = W1 + (size_t)e0 * D3 + blk * H;
    int tid = threadIdx.x;
    int tx = tid & 15, ty = tid >> 4;
    float4 pa[2], pb[4];
#pragma unroll
    for (int j = 0; j < 2; j++) {
        int f = tid + 256 * j;
        pa[j] = *(const float4*)(Ap + (size_t)(f >> 3) * H + (f & 7) * 4);
    }
#pragma unroll
    for (int j = 0; j < 4; j++) {
        int f = tid + 256 * j;
        pb[j] = *(const float4*)(Bp + (size_t)(f >> 3) * D3 + (f & 7) * 4);
    }
    float acc[4][8];
#pragma unroll
    for (int r = 0; r < 4; r++)
#pragma unroll
        for (int c = 0; c < 8; c++) acc[r][c] = 0.f;
    for (int kt = 0; kt < H; kt += 32) {
#pragma unroll
        for (int j = 0; j < 2; j++) {
            int f = tid + 256 * j;
            int row = f >> 3, c4 = (f & 7) * 4;
            As[c4 + 0][row] = pa[j].x; As[c4 + 1][row] = pa[j].y;
            As[c4 + 2][row] = pa[j].z; As[c4 + 3][row] = pa[j].w;
        }
#pragma unroll
        for (int j = 0; j < 4; j++) {
            int f = tid + 256 * j;
            int row = f >> 3, c4 = (f & 7) * 4;
            Bs[c4 + 0][row] = pb[j].x; Bs[c4 + 1][row] = pb[j].y;
            Bs[c4 + 2][row] = pb[j].z; Bs[c4 + 3][row] = pb[j].w;
        }
        __syncthreads();
        if (kt + 32 < H) {
            int kn = kt + 32;
#pragma unroll
            for (int j = 0; j < 2; j++) {
                int f = tid + 256 * j;
                pa[j] = *(const float4*)(Ap + (size_t)(f >> 3) * H + kn + (f & 7) * 4);
            }
#pragma unroll
            for (int j = 0; j < 4; j++) {
                int f = tid + 256 * j;
                pb[j] = *(const float4*)(Bp + (size_t)(f >> 3) * D3 + kn + (f & 7) * 4);
            }
        }
#pragma unroll
        for (int k = 0; k < 32; k++) {
            float4 a  = *(const float4*)&As[k][ty * 4];
            float4 b0 = *(const float4*)&Bs[k][tx * 8];
            float4 b1 = *(const float4*)&Bs[k][tx * 8 + 4];
            float av[4] = {a.x, a.y, a.z, a.w};
            float bv[8] = {b0.x, b0.y, b0.z, b0.w, b1.x, b1.y, b1.z, b1.w};
#pragma unroll
            for (int r = 0; r < 4; r++)
#pragma unroll
                for (int c = 0; c < 8; c++) acc[r][c] = fmaf(av[r], bv[c], acc[r][c]);
        }
        __syncthreads();
    }
#pragma unroll
    for (int r = 0; r < 4; r++) {
        float* gp = G + (size_t)(m0 + ty * 4 + r) * N6 + n0 + tx * 8;
        *(float4*)gp       = make_float4(acc[r][0], acc[r][1], acc[r][2], acc[r][3]);
        *(float4*)(gp + 4) = make_float4(acc[r][4], acc[r][5], acc[r][6], acc[r][7]);
    }
}

// ---------------------------------------------------------------- per-start span group: softmax, mention, sj/si
__global__ __launch_bounds__(256) void k_span(
    const float* __restrict__ G, const float* __restrict__ tokd,
    const float* __restrict__ b1, const float* __restrict__ w2,
    const float* __restrict__ b2, float* __restrict__ ment,
    float* __restrict__ sjA, float* __restrict__ siA) {
    int b = blockIdx.x / S, start = blockIdx.x % S;
    int nw = min(W, S - start);
    int tail = S - start;
    int base = (start <= S - W) ? start * W
             : (S - W + 1) * W + ((W - 1) * W / 2 - tail * (tail + 1) / 2);
    __shared__ float sc[W];
    __shared__ float aw[W][W];
    __shared__ float redA[4][W];
    int tid = threadIdx.x;
    if (tid < nw) sc[tid] = tokd[(size_t)(b * S + start + tid) * 8];
    __syncthreads();
    if (tid < nw) {
        int w = tid;  // span of width w+1
        float mx = sc[0];
        for (int j = 1; j <= w; j++) mx = fmaxf(mx, sc[j]);
        float sum = 0.f;
        for (int j = 0; j <= w; j++) { float e = expf(sc[j] - mx); aw[w][j] = e; sum += e; }
        float inv = 1.f / sum;
        for (int j = 0; j <= w; j++) aw[w][j] *= inv;
        const float* td = tokd + (size_t)(b * S) * 8;
        float sj = td[start * 8 + 1] + td[(start + w) * 8 + 2];
        float si = td[start * 8 + 4] + td[(start + w) * 8 + 5];
        for (int j = 0; j <= w; j++) {
            sj = fmaf(aw[w][j], td[(start + j) * 8 + 3], sj);
            si = fmaf(aw[w][j], td[(start + j) * 8 + 6], si);
        }
        sjA[b * NSPAN + base + w] = sj;
        siA[b * NSPAN + base + w] = si;
    }
    __syncthreads();
    float mloc[W];
#pragma unroll
    for (int w = 0; w < W; w++) mloc[w] = 0.f;
    const float* Gb = G + (size_t)(b * S) * N6;
    for (int e = tid; e < D3; e += 256) {
        float a = Gb[(size_t)start * N6 + e] + b1[e];
        float w2e = w2[e];
        float cj[W], bm[W];
#pragma unroll
        for (int j = 0; j < W; j++) {
            if (j < nw) {
                cj[j] = Gb[(size_t)(start + j) * N6 + 2 * D3 + e];
                bm[j] = Gb[(size_t)(start + j) * N6 + D3 + e];
            } else { cj[j] = 0.f; bm[j] = 0.f; }
        }
#pragma unroll
        for (int w = 0; w < W; w++) {
            if (w < nw) {
                float pre = a + bm[w];
#pragma unroll
                for (int j = 0; j <= w; j++) pre = fmaf(aw[w][j], cj[j], pre);
                mloc[w] += fmaxf(pre, 0.f) * w2e;
            }
        }
    }
    int wave = tid >> 6, lane = tid & 63;
#pragma unroll
    for (int w = 0; w < W; w++) {
        float v = mloc[w];
#pragma unroll
        for (int d = 32; d; d >>= 1) v += __shfl_down(v, d);
        if (lane == 0) redA[wave][w] = v;
    }
    __syncthreads();
    if (tid < nw)
        ment[b * NSPAN + base + tid] =
            redA[0][tid] + redA[1][tid] + redA[2][tid] + redA[3][tid] + b2[0];
}

// ---------------------------------------------------------------- top-k via radix select (stable, desc, ties -> lower idx)
__global__ __launch_bounds__(256) void k_topk(
    const float* __restrict__ ment, const float* __restrict__ sjA,
    const float* __restrict__ siA, float* __restrict__ selj, float* __restrict__ seli) {
    __shared__ unsigned int uv[NSPAN];
    __shared__ int hist[256];
    __shared__ int suf[256];
    __shared__ int cand_i[160];
    __shared__ unsigned int cand_u[160];
    __shared__ int ncand;
    __shared__ unsigned int s_prefix;
    __shared__ int s_kk;
    int b = blockIdx.x, tid = threadIdx.x;
    for (int n = tid; n < NSPAN; n += 256) {
        unsigned int u = __float_as_uint(ment[b * NSPAN + n]);
        uv[n] = (u & 0x80000000u) ? ~u : (u | 0x80000000u);
    }
    if (tid == 0) { s_prefix = 0u; s_kk = KTOP; ncand = 0; }
    __syncthreads();
    for (int pass = 3; pass >= 0; pass--) {
        int shift = pass * 8;
        hist[tid] = 0;
        __syncthreads();
        unsigned int pref = s_prefix;
        unsigned int pmask = (pass == 3) ? 0u : (0xFFFFFFFFu << (shift + 8));
        for (int n = tid; n < NSPAN; n += 256) {
            unsigned int u = uv[n];
            if ((u & pmask) == pref) atomicAdd(&hist[(u >> shift) & 255], 1);
        }
        __syncthreads();
        suf[tid] = hist[tid];
        __syncthreads();
        for (int d2 = 1; d2 < 256; d2 <<= 1) {
            int y = suf[tid] + ((tid + d2 < 256) ? suf[tid + d2] : 0);
            __syncthreads();
            suf[tid] = y;
            __syncthreads();
        }
        int kk = s_kk;
        __syncthreads();
        if (suf[tid] >= kk && (tid == 255 || suf[tid + 1] < kk)) {
            s_prefix = pref | ((unsigned int)tid << shift);
            s_kk = kk - ((tid == 255) ? 0 : suf[tid + 1]);
        }
        __syncthreads();
    }
    unsigned int uk = s_prefix;   // exact k-th largest key
    for (int n = tid; n < NSPAN; n += 256) {
        if (uv[n] >= uk) {
            int p = atomicAdd(&ncand, 1);
            if (p < 160) { cand_i[p] = n; cand_u[p] = uv[n]; }
        }
    }
    __syncthreads();
    int nc = min(ncand, 160);
    for (int c = tid; c < nc; c += 256) {
        unsigned int u = cand_u[c];
        int idx = cand_i[c];
        int rank = 0;
        for (int d = 0; d < nc; d++) {
            unsigned int ud = cand_u[d];
            if (ud > u || (ud == u && cand_i[d] < idx)) rank++;
        }
        if (rank < KTOP) {
            selj[b * KTOP + rank] = sjA[b * NSPAN + idx];
            seli[b * KTOP + rank] = siA[b * NSPAN + idx];
        }
    }
}

// ---------------------------------------------------------------- antecedent matrix + log-softmax
__global__ __launch_bounds__(128) void k_ant(
    const float* __restrict__ selj, const float* __restrict__ seli,
    const float* __restrict__ antb, float* __restrict__ out) {
    int b = blockIdx.x / KTOP, i = blockIdx.x % KTOP;
    int c = threadIdx.x;
    float v = -3.0e38f;
    if (c == 0) v = 0.f;
    else if (c <= KTOP) {
        int j = c - 1;
        v = (j >= i) ? -1e10f : (selj[b * KTOP + j] + seli[b * KTOP + i] + antb[0]);
    }
    __shared__ float r2[2];
    int wave = c >> 6, lane = c & 63;
    float mv = v;
#pragma unroll
    for (int d = 32; d; d >>= 1) mv = fmaxf(mv, __shfl_down(mv, d));
    if (lane == 0) r2[wave] = mv;
    __syncthreads();
    float mx = fmaxf(r2[0], r2[1]);
    __syncthreads();
    float ex = (c <= KTOP) ? expf(v - mx) : 0.f;
    float sv = ex;
#pragma unroll
    for (int d = 32; d; d >>= 1) sv += __shfl_down(sv, d);
    if (lane == 0) r2[wave] = sv;
    __syncthreads();
    float sm = r2[0] + r2[1];
    if (c <= KTOP)
        out[(size_t)(b * KTOP + i) * (KTOP + 1) + c] = logf(ex / sm + 1e-10f);
}

extern "C" void kernel_launch(void* const* d_in, const int* in_sizes, int n_in,
                              void* d_out, int out_size, void* d_ws, size_t ws_size,
                              hipStream_t stream) {
    (void)in_sizes; (void)n_in; (void)out_size; (void)ws_size;
    const float* hidden = (const float*)d_in[0];
    const int*   esrc   = (const int*)d_in[2];
    const int*   etgt   = (const int*)d_in[3];
    const int*   elab   = (const int*)d_in[4];
    const float* gcnW   = (const float*)d_in[5];
    const float* gcnb   = (const float*)d_in[6];
    const float* attnw  = (const float*)d_in[7];
    const float* msW1   = (const float*)d_in[9];
    const float* msb1   = (const float*)d_in[10];
    const float* msw2   = (const float*)d_in[11];
    const float* msb2   = (const float*)d_in[12];
    const float* antw   = (const float*)d_in[13];
    const float* antb   = (const float*)d_in[14];
    float* out = (float*)d_out;

    float* wsf  = (float*)d_ws;
    float* gout = wsf + OFF_GOUT;
    float* emb  = wsf + OFF_EMB;
    float* G    = wsf + OFF_G;
    float* tokd = wsf + OFF_TOKD;
    float* ment = wsf + OFF_MENT;
    float* sjA  = wsf + OFF_SJ;
    float* siA  = wsf + OFF_SI;
    float* selj = wsf + OFF_SELJ;
    float* seli = wsf + OFF_SELI;
    int* wsi   = (int*)(wsf + OFF_INT);
    int* cnt   = wsi;
    int* off   = wsi + 64;
    int* edges = wsi + 128;

    hipMemsetAsync(gout, 0, (size_t)B * S * H * sizeof(float), stream);
    k_group<<<1, B * E, 0, stream>>>(esrc, etgt, elab, cnt, off, edges);
    k_gcn<<<dim3(12, L, 2), 256, 0, stream>>>(hidden, gcnW, gcnb, cnt, off, edges, esrc, etgt, gout);
    k_embdots<<<B * S / 4, 256, 0, stream>>>(hidden, gout, attnw, antw, emb, tokd);
    k_gemm<<<dim3(N6 / 128, B * S / 64), 256, 0, stream>>>(emb, msW1, G);
    k_span<<<B * S, 256, 0, stream>>>(G, tokd, msb1, msw2, msb2, ment, sjA, siA);
    k_topk<<<B, 256, 0, stream>>>(ment, sjA, siA, selj, seli);
    k_ant<<<B * KTOP, 128, 0, stream>>>(selj, seli, antb, out);
}